// Round 6
// baseline (253.186 us; speedup 1.0000x reference)
//
#include <hip/hip_runtime.h>

#define B_   8
#define CIN  8
#define COUT 32
#define H_   128
#define W_   128
#define OH   126
#define OW   126
#define NPIX (B_ * OH * OW)   // 127008

// ---------------------------------------------------------------------------
// Kernel 1: conv + bias for the first CIN=8 output channels.
// Block = 256 threads = 4 waves over 64 pixels. Wave `wid` handles input
// channels {2*wid, 2*wid+1} (partial sums), LDS sum-reduce adds bias and
// stores y. Splits both the loads (18/thread) and FMAs (144/thread) 4-way
// with ZERO load redundancy -> 4x the waves of round-1 conv.
// ---------------------------------------------------------------------------
__global__ __launch_bounds__(256, 4) void conv_y_kernel(
    const float* __restrict__ x, const float* __restrict__ w,
    const float* __restrict__ bias, float* __restrict__ y) {
  int t = threadIdx.x;
  int lane = t & 63;
  int wid = __builtin_amdgcn_readfirstlane(t >> 6);  // wave-uniform 0..3
  int pix = blockIdx.x * 64 + lane;
  int pc = pix < NPIX ? pix : NPIX - 1;   // clamp for loads only
  int j = pc % OW;
  int t2 = pc / OW;
  int i = t2 % OH;
  int b = t2 / OH;

  int ci0 = wid * 2;
  float acc[CIN];
#pragma unroll
  for (int c = 0; c < CIN; ++c) acc[c] = 0.f;

#pragma unroll
  for (int cc = 0; cc < 2; ++cc) {
    int ci = ci0 + cc;
    const float* xp = x + ((long)(b * CIN + ci) * H_ + i) * W_ + j;
#pragma unroll
    for (int kh = 0; kh < 3; ++kh) {
      const float* xr = xp + kh * W_;
      float x0 = xr[0];
      float x1 = xr[1];
      float x2 = xr[2];
#pragma unroll
      for (int c = 0; c < CIN; ++c) {
        const float* wp = w + ((c * CIN + ci) * 3 + kh) * 3;  // uniform -> s_load
        acc[c] = fmaf(x2, wp[2], fmaf(x1, wp[1], fmaf(x0, wp[0], acc[c])));
      }
    }
  }

  // LDS partial-sum exchange; pad row to 9 floats (9 coprime 32 -> no bank conflict)
  __shared__ float part[4 * 64 * 9];
#pragma unroll
  for (int c = 0; c < CIN; ++c) part[(wid * 64 + lane) * 9 + c] = acc[c];
  __syncthreads();

  // reduce: thread t -> pixel t&63, channel pair t>>6
  int rp = t & 63;
  int cpair = t >> 6;
  int opix = blockIdx.x * 64 + rp;
  if (opix < NPIX) {
    int oj = opix % OW;
    int ot = opix / OW;
    int oi = ot % OH;
    int ob = ot / OH;
#pragma unroll
    for (int cc = 0; cc < 2; ++cc) {
      int c = cpair * 2 + cc;
      float s = bias[c];
#pragma unroll
      for (int ww = 0; ww < 4; ++ww) s += part[(ww * 64 + rp) * 9 + c];
      y[((long)(ob * CIN + c) * OH + oi) * OW + oj] = s;
    }
  }
}

// ---------------------------------------------------------------------------
// Kernel 2: out[p] = 2 * min_o max_{valid tap k, c} y[c, p+k] * w[o,c,k]
// Block = 256 threads = 4 waves over 64 pixels. Wave `wid` handles output
// channels [8*wid, 8*wid+8); LDS min-reduce across the 4 waves.
// Weights per o are 72 contiguous dwords at a wave-uniform address -> s_load.
// ---------------------------------------------------------------------------
__global__ __launch_bounds__(256, 4) void stage2_kernel(
    const float* __restrict__ y, const float* __restrict__ w,
    float* __restrict__ out) {
  int t = threadIdx.x;
  int lane = t & 63;
  int wid = __builtin_amdgcn_readfirstlane(t >> 6);  // wave-uniform 0..3
  int pix = blockIdx.x * 64 + lane;
  int pc = pix < NPIX ? pix : NPIX - 1;   // clamp for loads only
  int j = pc % OW;
  int t2 = pc / OW;
  int i = t2 % OH;
  int b = t2 / OH;

  bool v1h = (i + 1) < OH, v2h = (i + 2) < OH;
  bool v1w = (j + 1) < OW, v2w = (j + 2) < OW;
  int i1 = v1h ? i + 1 : i, i2 = v2h ? i + 2 : i;
  int j1 = v1w ? j + 1 : j, j2 = v2w ? j + 2 : j;

  const float* yb = y + (long)b * CIN * (OH * OW);
  float tv[CIN][9];
#pragma unroll
  for (int c = 0; c < CIN; ++c) {
    const float* yc = yb + c * (OH * OW);
    const float* r0 = yc + i  * OW;
    const float* r1 = yc + i1 * OW;
    const float* r2 = yc + i2 * OW;
    tv[c][0] = r0[j];  tv[c][1] = r0[j1]; tv[c][2] = r0[j2];
    tv[c][3] = r1[j];  tv[c][4] = r1[j1]; tv[c][5] = r1[j2];
    tv[c][6] = r2[j];  tv[c][7] = r2[j1]; tv[c][8] = r2[j2];
  }

  bool vt1 = v1w, vt2 = v2w;
  bool vt3 = v1h, vt4 = v1h && v1w, vt5 = v1h && v2w;
  bool vt6 = v2h, vt7 = v2h && v1w, vt8 = v2h && v2w;

  const float NI = -__builtin_inff();
  float mn = __builtin_inff();

#pragma unroll 2
  for (int oo = 0; oo < 8; ++oo) {
    const float* wo = w + (long)(wid * 8 + oo) * (CIN * 9);  // 72 contiguous, uniform
    float m[9];
#pragma unroll
    for (int k = 0; k < 9; ++k) m[k] = tv[0][k] * wo[k];     // c = 0 init
#pragma unroll
    for (int c = 1; c < CIN; ++c) {
#pragma unroll
      for (int k = 0; k < 9; ++k) {
        m[k] = fmaxf(m[k], tv[c][k] * wo[c * 9 + k]);
      }
    }
    float z1 = vt1 ? m[1] : NI, z2 = vt2 ? m[2] : NI, z3 = vt3 ? m[3] : NI;
    float z4 = vt4 ? m[4] : NI, z5 = vt5 ? m[5] : NI, z6 = vt6 ? m[6] : NI;
    float z7 = vt7 ? m[7] : NI, z8 = vt8 ? m[8] : NI;
    // nested for v_max3 fusion
    float mx = fmaxf(fmaxf(fmaxf(m[0], z1), fmaxf(z2, z3)),
                     fmaxf(fmaxf(z4, z5), fmaxf(z6, z7)));
    mx = fmaxf(mx, z8);
    mn = fminf(mn, mx);
  }

  __shared__ float red[4][64];
  red[wid][lane] = mn;
  __syncthreads();
  if (t < 64) {
    int opix = blockIdx.x * 64 + t;
    if (opix < NPIX) {
      float r = fminf(fminf(red[0][t], red[1][t]), fminf(red[2][t], red[3][t]));
      out[opix] = 2.0f * r;
    }
  }
}

extern "C" void kernel_launch(void* const* d_in, const int* in_sizes, int n_in,
                              void* d_out, int out_size, void* d_ws, size_t ws_size,
                              hipStream_t stream) {
  const float* x    = (const float*)d_in[0];  // (8,8,128,128)
  const float* w    = (const float*)d_in[1];  // (32,8,3,3)
  const float* bias = (const float*)d_in[2];  // (32,)
  float* out = (float*)d_out;                 // (8,1,126,126) fp32
  float* y   = (float*)d_ws;                  // 8*8*126*126*4 = 4.06 MB scratch

  const int blocks = (NPIX + 63) / 64;        // 64 pixels per 256-thread block
  conv_y_kernel<<<blocks, 256, 0, stream>>>(x, w, bias, y);
  stage2_kernel<<<blocks, 256, 0, stream>>>(y, w, out);
}